// Round 1
// baseline (27302.359 us; speedup 1.0000x reference)
//
#include <hip/hip_runtime.h>
#include <hip/hip_bf16.h>

#define EPS_BN 1e-5f

constexpr int B  = 2048, F0 = 64, K = 14;
constexpr int C1 = 64,  F1 = 32;
constexpr int C2 = 128, F2 = 16;
constexpr int C3 = 256, F3 = 8;

__device__ __forceinline__ float bf2f(unsigned short u) {
    union { unsigned int i; float f; } x; x.i = ((unsigned int)u) << 16; return x.f;
}
__device__ __forceinline__ unsigned short f2bf(float f) {
    union { float f; unsigned int i; } x; x.f = f;
    unsigned int r = (x.i + 0x7fffu + ((x.i >> 16) & 1u)) >> 16;
    return (unsigned short)r;
}

// ---- fold BN into conv1 weights ----
__global__ void repack_w1(const float* __restrict__ w1, const float* __restrict__ g,
                          const float* __restrict__ bb, const float* __restrict__ m,
                          const float* __restrict__ v, float* __restrict__ w1f,
                          float* __restrict__ t1) {
    int i = blockIdx.x * 256 + threadIdx.x;
    if (i < C1) {
        float s = g[i] * rsqrtf(v[i] + EPS_BN);
        t1[i] = bb[i] - m[i] * s;
    }
    if (i < C1 * 2 * 9) {
        int c = i / 18;
        float s = g[c] * rsqrtf(v[c] + EPS_BN);
        w1f[i] = w1[i] * s;
    }
}

// ---- transpose w (OIHW -> [cin*9][cout]) and fold BN scale ----
template<int CIN, int COUT>
__global__ void repack_w(const float* __restrict__ w, const float* __restrict__ g,
                         const float* __restrict__ bb, const float* __restrict__ m,
                         const float* __restrict__ v, float* __restrict__ wt,
                         float* __restrict__ t) {
    int i = blockIdx.x * 256 + threadIdx.x;
    if (i < COUT) {
        float s = g[i] * rsqrtf(v[i] + EPS_BN);
        t[i] = bb[i] - m[i] * s;
    }
    if (i < CIN * 9 * COUT) {
        int co = i % COUT;     // COUT is power of 2
        int j  = i / COUT;     // j = c*9 + r, r = df*3+dk
        int c  = j / 9, r = j % 9;
        float s = g[co] * rsqrtf(v[co] + EPS_BN);
        wt[i] = w[(co * CIN + c) * 9 + r] * s;
    }
}

// ---- conv1 (2->64, 3x3, stride (2,1), pad 1) + BN + ReLU, NHWC bf16 out ----
__global__ void conv1_kernel(const float* __restrict__ x, const float* __restrict__ sig,
                             const float* __restrict__ w1f, const float* __restrict__ t1,
                             unsigned short* __restrict__ h1) {
    int gid = blockIdx.x * 256 + threadIdx.x;   // B*F1*K*C1 threads
    int c = gid & 63;
    int rest = gid >> 6;
    int k = rest % K;
    rest /= K;
    int f = rest & (F1 - 1);
    int b = rest >> 5;
    float acc = t1[c];
    #pragma unroll
    for (int df = 0; df < 3; ++df) {
        int fi = 2 * f + df - 1;
        if (fi < 0 || fi >= F0) continue;
        #pragma unroll
        for (int dk = 0; dk < 3; ++dk) {
            int ki = k + dk - 1;
            if (ki < 0 || ki >= K) continue;
            float xv = x[(b * F0 + fi) * K + ki];
            float sv = sig[(b * F0 + fi) * K + ki] * 10.0f;
            acc = fmaf(xv, w1f[(c * 2 + 0) * 9 + df * 3 + dk], acc);
            acc = fmaf(sv, w1f[(c * 2 + 1) * 9 + df * 3 + dk], acc);
        }
    }
    h1[gid] = f2bf(fmaxf(acc, 0.0f));
}

// ---- conv2/conv3 (CIN->COUT, 3x3, stride (2,1), pad 1) + BN + ReLU ----
// block = (f_out, b); COUT/2 threads; each thread: channels t and t+COUT/2, all 14 cols
template<int CIN, int COUT, int FIN>
__global__ void conv_mid(const unsigned short* __restrict__ hin,
                         const float* __restrict__ wt, const float* __restrict__ tb,
                         unsigned short* __restrict__ hout) {
    constexpr int TH = COUT / 2;
    int f2 = blockIdx.x;       // 0..FIN/2-1
    int b  = blockIdx.y;
    int t  = threadIdx.x;
    __shared__ float lin[3 * K * CIN];

    // stage 3 input rows (2f2-1 .. 2f2+1) as fp32; zero-fill padding row
    for (int i = t; i < 3 * K * CIN / 2; i += TH) {
        int e   = i * 2;
        int df  = e / (K * CIN);
        int rem = e % (K * CIN);
        int fi  = 2 * f2 + df - 1;
        float a0 = 0.f, a1 = 0.f;
        if (fi >= 0 && fi < FIN) {
            unsigned int u = *(const unsigned int*)(hin + (size_t)(b * FIN + fi) * (K * CIN) + rem);
            a0 = bf2f((unsigned short)(u & 0xffffu));
            a1 = bf2f((unsigned short)(u >> 16));
        }
        lin[e] = a0; lin[e + 1] = a1;
    }
    __syncthreads();

    float acc0[K], acc1[K];
    float t0 = tb[t], t1v = tb[t + TH];
    #pragma unroll
    for (int k = 0; k < K; ++k) { acc0[k] = t0; acc1[k] = t1v; }

    for (int df = 0; df < 3; ++df) {
        for (int cc = 0; cc < CIN / 8; ++cc) {
            float w0[8][3], w1[8][3];
            #pragma unroll
            for (int j = 0; j < 8; ++j)
                #pragma unroll
                for (int dk = 0; dk < 3; ++dk) {
                    int widx = ((cc * 8 + j) * 9 + df * 3 + dk) * COUT;
                    w0[j][dk] = wt[widx + t];
                    w1[j][dk] = wt[widx + t + TH];
                }
            #pragma unroll
            for (int kin = 0; kin < K; ++kin) {
                const float* vp = &lin[(df * K + kin) * CIN + cc * 8];
                float4 va = *(const float4*)(vp);
                float4 vb = *(const float4*)(vp + 4);
                float vv[8] = {va.x, va.y, va.z, va.w, vb.x, vb.y, vb.z, vb.w};
                #pragma unroll
                for (int j = 0; j < 8; ++j) {
                    #pragma unroll
                    for (int dk = 0; dk < 3; ++dk) {
                        int k2 = kin + 1 - dk;
                        if (k2 >= 0 && k2 < K) {
                            acc0[k2] = fmaf(vv[j], w0[j][dk], acc0[k2]);
                            acc1[k2] = fmaf(vv[j], w1[j][dk], acc1[k2]);
                        }
                    }
                }
            }
        }
    }

    size_t base = ((size_t)(b * (FIN / 2) + f2) * K) * COUT;
    #pragma unroll
    for (int k = 0; k < K; ++k) {
        hout[base + k * COUT + t]      = f2bf(fmaxf(acc0[k], 0.f));
        hout[base + k * COUT + t + TH] = f2bf(fmaxf(acc1[k], 0.f));
    }
}

// ---- conv4 (256->2, kernel (8,1)) + transpose to [B,K,2] ----
__global__ void conv4_kernel(const unsigned short* __restrict__ h3,
                             const float* __restrict__ w4, float* __restrict__ out) {
    int b = blockIdx.x;
    int t = threadIdx.x;   // 256 = C3
    float wa[8], wb[8];
    #pragma unroll
    for (int f = 0; f < 8; ++f) {
        wa[f] = w4[(0 * C3 + t) * 8 + f];
        wb[f] = w4[(1 * C3 + t) * 8 + f];
    }
    float p0[K], p1[K];
    #pragma unroll
    for (int k = 0; k < K; ++k) { p0[k] = 0.f; p1[k] = 0.f; }
    for (int f = 0; f < 8; ++f) {
        #pragma unroll
        for (int k = 0; k < K; ++k) {
            float v = bf2f(h3[((size_t)(b * F3 + f) * K + k) * C3 + t]);
            p0[k] = fmaf(v, wa[f], p0[k]);
            p1[k] = fmaf(v, wb[f], p1[k]);
        }
    }
    __shared__ float red[4][2 * K];
    int lane = t & 63, wv = t >> 6;
    #pragma unroll
    for (int k = 0; k < K; ++k) {
        float a = p0[k], c = p1[k];
        #pragma unroll
        for (int off = 32; off > 0; off >>= 1) {
            a += __shfl_down(a, off, 64);
            c += __shfl_down(c, off, 64);
        }
        if (lane == 0) { red[wv][k * 2 + 0] = a; red[wv][k * 2 + 1] = c; }
    }
    __syncthreads();
    if (t < 2 * K) {
        out[b * (2 * K) + t] = red[0][t] + red[1][t] + red[2][t] + red[3][t];
    }
}

extern "C" void kernel_launch(void* const* d_in, const int* in_sizes, int n_in,
                              void* d_out, int out_size, void* d_ws, size_t ws_size,
                              hipStream_t stream) {
    const float* x   = (const float*)d_in[0];
    const float* sig = (const float*)d_in[1];
    const float* w1  = (const float*)d_in[2];
    const float* w2  = (const float*)d_in[3];
    const float* w3  = (const float*)d_in[4];
    const float* w4  = (const float*)d_in[5];
    const float* g1  = (const float*)d_in[6];
    const float* b1  = (const float*)d_in[7];
    const float* m1  = (const float*)d_in[8];
    const float* v1  = (const float*)d_in[9];
    const float* g2  = (const float*)d_in[10];
    const float* b2  = (const float*)d_in[11];
    const float* m2  = (const float*)d_in[12];
    const float* v2  = (const float*)d_in[13];
    const float* g3  = (const float*)d_in[14];
    const float* b3  = (const float*)d_in[15];
    const float* m3  = (const float*)d_in[16];
    const float* v3  = (const float*)d_in[17];

    char* ws = (char*)d_ws;
    size_t off = 0;
    auto alloc = [&](size_t bytes) {
        char* p = ws + off;
        off += (bytes + 255) & ~(size_t)255;
        return p;
    };
    unsigned short* h1 = (unsigned short*)alloc((size_t)B * F1 * K * C1 * 2);  // 117.4 MB, reused for h3
    unsigned short* h2 = (unsigned short*)alloc((size_t)B * F2 * K * C2 * 2);  // 117.4 MB
    float* w1f = (float*)alloc((size_t)C1 * 2 * 9 * 4);
    float* t1  = (float*)alloc((size_t)C1 * 4);
    float* w2t = (float*)alloc((size_t)C1 * 9 * C2 * 4);
    float* t2  = (float*)alloc((size_t)C2 * 4);
    float* w3t = (float*)alloc((size_t)C2 * 9 * C3 * 4);
    float* t3  = (float*)alloc((size_t)C3 * 4);
    unsigned short* h3 = h1;

    repack_w1<<<(C1 * 2 * 9 + 255) / 256, 256, 0, stream>>>(w1, g1, b1, m1, v1, w1f, t1);
    repack_w<C1, C2><<<(C1 * 9 * C2 + 255) / 256, 256, 0, stream>>>(w2, g2, b2, m2, v2, w2t, t2);
    repack_w<C2, C3><<<(C2 * 9 * C3 + 255) / 256, 256, 0, stream>>>(w3, g3, b3, m3, v3, w3t, t3);

    conv1_kernel<<<(B * F1 * K * C1) / 256, 256, 0, stream>>>(x, sig, w1f, t1, h1);
    conv_mid<C1, C2, F1><<<dim3(F2, B), C2 / 2, 0, stream>>>(h1, w2t, t2, h2);
    conv_mid<C2, C3, F2><<<dim3(F3, B), C3 / 2, 0, stream>>>(h2, w3t, t3, h3);
    conv4_kernel<<<B, C3, 0, stream>>>(h3, w4, (float*)d_out);
}

// Round 2
// 523.826 us; speedup vs baseline: 52.1211x; 52.1211x over previous
//
#include <hip/hip_runtime.h>
#include <hip/hip_bf16.h>

#define EPS_BN 1e-5f

constexpr int B  = 2048, F0 = 64, K = 14;
constexpr int C1 = 64,  F1 = 32;
constexpr int C2 = 128, F2 = 16;
constexpr int C3 = 256, F3 = 8;

typedef __attribute__((ext_vector_type(8))) short bf16x8;
typedef __attribute__((ext_vector_type(4))) float f32x4;

__device__ __forceinline__ float bf2f(unsigned short u) {
    union { unsigned int i; float f; } x; x.i = ((unsigned int)u) << 16; return x.f;
}
__device__ __forceinline__ unsigned short f2bf(float f) {
    union { float f; unsigned int i; } x; x.f = f;
    unsigned int r = (x.i + 0x7fffu + ((x.i >> 16) & 1u)) >> 16;
    return (unsigned short)r;
}

// ---- fold BN into conv1 weights (fp32, layout [c][2][9] flat) ----
__global__ void repack_w1(const float* __restrict__ w1, const float* __restrict__ g,
                          const float* __restrict__ bb, const float* __restrict__ m,
                          const float* __restrict__ v, float* __restrict__ w1f,
                          float* __restrict__ t1) {
    int i = blockIdx.x * 256 + threadIdx.x;
    if (i < C1) {
        float s = g[i] * rsqrtf(v[i] + EPS_BN);
        t1[i] = bb[i] - m[i] * s;
    }
    if (i < C1 * 2 * 9) {
        int c = i / 18;
        float s = g[c] * rsqrtf(v[c] + EPS_BN);
        w1f[i] = w1[i] * s;
    }
}

// ---- repack conv weights into MFMA B-fragment layout, bf16, BN-folded ----
// wp[((chunk*COUT + n)*32) + kk] = W[tap][ci][n]*s[n], chunk=tap*(CIN/32)+cc, ci=cc*32+kk
template<int CIN, int COUT>
__global__ void repack_mfma(const float* __restrict__ w, const float* __restrict__ g,
                            const float* __restrict__ bb, const float* __restrict__ m,
                            const float* __restrict__ v, unsigned short* __restrict__ wp,
                            float* __restrict__ t) {
    int idx = blockIdx.x * 256 + threadIdx.x;
    if (idx < COUT) {
        float s = g[idx] * rsqrtf(v[idx] + EPS_BN);
        t[idx] = bb[idx] - m[idx] * s;
    }
    if (idx < 9 * CIN * COUT) {
        constexpr int CCS = CIN / 32;
        int kk = idx & 31;
        int rest = idx >> 5;
        int n = rest & (COUT - 1);
        int chunk = rest / COUT;        // COUT is power of 2
        int tap = chunk / CCS;          // CCS is power of 2
        int cc  = chunk & (CCS - 1);
        int ci = cc * 32 + kk;
        float s = g[n] * rsqrtf(v[n] + EPS_BN);
        wp[idx] = f2bf(w[(n * CIN + ci) * 9 + tap] * s);
    }
}

// ---- conv1 (2->64, 3x3, stride (2,1), pad 1) + BN + ReLU, NHWC bf16 out ----
// block per batch; x/sig/weights staged in LDS (broadcast reads)
__global__ void conv1_kernel(const float* __restrict__ x, const float* __restrict__ sig,
                             const float* __restrict__ w1f, const float* __restrict__ t1,
                             unsigned short* __restrict__ h1) {
    __shared__ float xs[F0 * K], ssg[F0 * K], wsh[C1 * 19], bsh[C1];
    int b = blockIdx.x, t = threadIdx.x;
    for (int i = t; i < F0 * K; i += 256) {
        xs[i]  = x[(size_t)b * F0 * K + i];
        ssg[i] = sig[(size_t)b * F0 * K + i] * 10.0f;
    }
    for (int i = t; i < C1 * 18; i += 256) {
        int c = i / 18, r = i % 18;
        wsh[c * 19 + r] = w1f[i];      // stride 19 -> 2-way banks only
    }
    if (t < C1) bsh[t] = t1[t];
    __syncthreads();
    int c = t & 63, pg = t >> 6;
    for (int p = pg; p < F1 * K; p += 4) {
        int f = p / K, k = p % K;
        float acc = bsh[c];
        #pragma unroll
        for (int df = 0; df < 3; ++df) {
            int fi = 2 * f + df - 1;
            if (fi < 0 || fi >= F0) continue;
            #pragma unroll
            for (int dk = 0; dk < 3; ++dk) {
                int ki = k + dk - 1;
                if (ki < 0 || ki >= K) continue;
                acc = fmaf(xs[fi * K + ki],  wsh[c * 19 + df * 3 + dk], acc);
                acc = fmaf(ssg[fi * K + ki], wsh[c * 19 + 9 + df * 3 + dk], acc);
            }
        }
        h1[(((size_t)b * F1 + f) * K + k) * C1 + c] = f2bf(fmaxf(acc, 0.f));
    }
}

// ---- conv2/conv3 as MFMA GEMM ----
// Block: 256 threads (4 waves), G=4 (b,f2) groups, wave owns COUT/4 columns.
// A staged in LDS: [g][df][p=kin+1 (16, clamped)][CIN+8 bf16]; B from global in
// fragment-native packed layout (L2-hot, reused across 4 groups in regs).
template<int CIN, int COUT, int FIN>
__launch_bounds__(256, 2)
__global__ void conv_mfma(const unsigned short* __restrict__ hin,
                          const unsigned short* __restrict__ wp,
                          const float* __restrict__ tb,
                          unsigned short* __restrict__ hout) {
    constexpr int G = 4;
    constexpr int RS = CIN + 8;          // +16B pad: row stride 2-way banks (free)
    constexpr int NT = COUT / 64;        // n-tiles per wave
    constexpr int CCS = CIN / 32;
    __shared__ alignas(16) unsigned short lin[G * 3 * 16 * RS];

    const int b = blockIdx.y;
    const int f2base = blockIdx.x * G;
    const int t = threadIdx.x;

    // zero all (covers k-pad positions p=0,15 and OOB rows)
    for (int i = t; i < G * 3 * 16 * RS / 8; i += 256)
        ((uint4*)lin)[i] = uint4{0, 0, 0, 0};
    __syncthreads();

    constexpr int CHW = CIN / 8;         // 16B chunks per row
    for (int i = t; i < G * 3 * 14 * CHW; i += 256) {
        int ci8 = (i & (CHW - 1)) * 8;
        int r = i / CHW;
        int kin = r % 14; r /= 14;
        int df = r % 3;  int gg = r / 3;
        int fi = 2 * (f2base + gg) + df - 1;
        if (fi >= 0 && fi < FIN) {
            uint4 val = *(const uint4*)(hin + (((size_t)(b * FIN + fi)) * K + kin) * CIN + ci8);
            *(uint4*)(&lin[((gg * 3 + df) * 16 + (kin + 1)) * RS + ci8]) = val;
        }
    }
    __syncthreads();

    const int lane = t & 63;
    const int wave = t >> 6;
    const int m = lane & 15;             // A row / B col / D col
    const int quad = lane >> 4;
    const int nBase = wave * (COUT / 4);

    f32x4 acc[G][NT];
    #pragma unroll
    for (int nt = 0; nt < NT; ++nt) {
        float bias = tb[nBase + nt * 16 + m];
        #pragma unroll
        for (int g = 0; g < G; ++g)
            acc[g][nt] = f32x4{bias, bias, bias, bias};
    }

    #pragma unroll
    for (int df = 0; df < 3; ++df) {
        #pragma unroll
        for (int dk = 0; dk < 3; ++dk) {
            int p = m + dk; p = (p > 15) ? 15 : p;   // clamp: pad rows read zeros/garbage (discarded)
            #pragma unroll
            for (int cc = 0; cc < CCS; ++cc) {
                const int chunk = (df * 3 + dk) * CCS + cc;
                bf16x8 av[G];
                #pragma unroll
                for (int g = 0; g < G; ++g)
                    av[g] = *(const bf16x8*)(&lin[((g * 3 + df) * 16 + p) * RS + cc * 32 + quad * 8]);
                bf16x8 bv[NT];
                #pragma unroll
                for (int nt = 0; nt < NT; ++nt)
                    bv[nt] = *(const bf16x8*)(wp + (((chunk * COUT + nBase + nt * 16 + m)) << 5) + quad * 8);
                #pragma unroll
                for (int g = 0; g < G; ++g)
                    #pragma unroll
                    for (int nt = 0; nt < NT; ++nt)
                        acc[g][nt] = __builtin_amdgcn_mfma_f32_16x16x32_bf16(av[g], bv[nt], acc[g][nt], 0, 0, 0);
            }
        }
    }

    // epilogue: D[row=quad*4+i][col=m], ReLU, bf16 NHWC store; rows 14,15 = pad
    #pragma unroll
    for (int g = 0; g < G; ++g) {
        size_t rowbase = ((size_t)(b * (FIN / 2) + f2base + g)) * K;
        #pragma unroll
        for (int nt = 0; nt < NT; ++nt) {
            int col = nBase + nt * 16 + m;
            #pragma unroll
            for (int i = 0; i < 4; ++i) {
                int row = quad * 4 + i;
                if (row < K)
                    hout[(rowbase + row) * COUT + col] = f2bf(fmaxf(acc[g][nt][i], 0.f));
            }
        }
    }
}

// ---- conv4 (256->2, kernel (8,1)) + transpose to [B,K,2] ----
__global__ void conv4_kernel(const unsigned short* __restrict__ h3,
                             const float* __restrict__ w4, float* __restrict__ out) {
    int b = blockIdx.x;
    int t = threadIdx.x;   // 256 = C3
    float wa[8], wb[8];
    #pragma unroll
    for (int f = 0; f < 8; ++f) {
        wa[f] = w4[(0 * C3 + t) * 8 + f];
        wb[f] = w4[(1 * C3 + t) * 8 + f];
    }
    float p0[K], p1[K];
    #pragma unroll
    for (int k = 0; k < K; ++k) { p0[k] = 0.f; p1[k] = 0.f; }
    for (int f = 0; f < 8; ++f) {
        #pragma unroll
        for (int k = 0; k < K; ++k) {
            float v = bf2f(h3[((size_t)(b * F3 + f) * K + k) * C3 + t]);
            p0[k] = fmaf(v, wa[f], p0[k]);
            p1[k] = fmaf(v, wb[f], p1[k]);
        }
    }
    __shared__ float red[4][2 * K];
    int lane = t & 63, wv = t >> 6;
    #pragma unroll
    for (int k = 0; k < K; ++k) {
        float a = p0[k], c = p1[k];
        #pragma unroll
        for (int off = 32; off > 0; off >>= 1) {
            a += __shfl_down(a, off, 64);
            c += __shfl_down(c, off, 64);
        }
        if (lane == 0) { red[wv][k * 2 + 0] = a; red[wv][k * 2 + 1] = c; }
    }
    __syncthreads();
    if (t < 2 * K) {
        out[b * (2 * K) + t] = red[0][t] + red[1][t] + red[2][t] + red[3][t];
    }
}

extern "C" void kernel_launch(void* const* d_in, const int* in_sizes, int n_in,
                              void* d_out, int out_size, void* d_ws, size_t ws_size,
                              hipStream_t stream) {
    const float* x   = (const float*)d_in[0];
    const float* sig = (const float*)d_in[1];
    const float* w1  = (const float*)d_in[2];
    const float* w2  = (const float*)d_in[3];
    const float* w3  = (const float*)d_in[4];
    const float* w4  = (const float*)d_in[5];
    const float* g1  = (const float*)d_in[6];
    const float* b1  = (const float*)d_in[7];
    const float* m1  = (const float*)d_in[8];
    const float* v1  = (const float*)d_in[9];
    const float* g2  = (const float*)d_in[10];
    const float* b2  = (const float*)d_in[11];
    const float* m2  = (const float*)d_in[12];
    const float* v2  = (const float*)d_in[13];
    const float* g3  = (const float*)d_in[14];
    const float* b3  = (const float*)d_in[15];
    const float* m3  = (const float*)d_in[16];
    const float* v3  = (const float*)d_in[17];

    char* ws = (char*)d_ws;
    size_t off = 0;
    auto alloc = [&](size_t bytes) {
        char* p = ws + off;
        off += (bytes + 255) & ~(size_t)255;
        return p;
    };
    unsigned short* h1  = (unsigned short*)alloc((size_t)B * F1 * K * C1 * 2);  // reused as h3
    unsigned short* h2  = (unsigned short*)alloc((size_t)B * F2 * K * C2 * 2);
    float* w1f = (float*)alloc((size_t)C1 * 2 * 9 * 4);
    float* t1  = (float*)alloc((size_t)C1 * 4);
    unsigned short* wp2 = (unsigned short*)alloc((size_t)9 * C1 * C2 * 2);
    float* t2  = (float*)alloc((size_t)C2 * 4);
    unsigned short* wp3 = (unsigned short*)alloc((size_t)9 * C2 * C3 * 2);
    float* t3  = (float*)alloc((size_t)C3 * 4);
    unsigned short* h3 = h1;

    repack_w1<<<(C1 * 2 * 9 + 255) / 256, 256, 0, stream>>>(w1, g1, b1, m1, v1, w1f, t1);
    repack_mfma<C1, C2><<<(9 * C1 * C2 + 255) / 256, 256, 0, stream>>>(w2, g2, b2, m2, v2, wp2, t2);
    repack_mfma<C2, C3><<<(9 * C2 * C3 + 255) / 256, 256, 0, stream>>>(w3, g3, b3, m3, v3, wp3, t3);

    conv1_kernel<<<B, 256, 0, stream>>>(x, sig, w1f, t1, h1);
    conv_mfma<C1, C2, F1><<<dim3(F2 / 2 / 4 * 2, B), 256, 0, stream>>>(h1, wp2, t2, h2);   // (4, B)
    conv_mfma<C2, C3, F2><<<dim3(F3 / 2 / 4 * 2, B), 256, 0, stream>>>(h2, wp3, t3, h3);   // (2, B)
    conv4_kernel<<<B, 256, 0, stream>>>(h3, w4, (float*)d_out);
}